// Round 3
// baseline (22760.104 us; speedup 1.0000x reference)
//
#include <hip/hip_runtime.h>
#include <math.h>

namespace {

constexpr int Bb = 1024;
constexpr int Tn = 64;
constexpr int Dn = 8;
constexpr int Hn = 64;
constexpr int Wn = 128;
constexpr int BT = 4;     // batch rows per block
constexpr int NT = 1024;  // threads per block (16 waves)

// Tsit5 tableau
constexpr float A21 = 0.161f;
constexpr float A31 = -0.008480655492356989f, A32 = 0.335480655492357f;
constexpr float A41 = 2.8971530571054935f, A42 = -6.359448489975075f, A43 = 4.3622954328695815f;
constexpr float A51 = 5.325864828439257f, A52 = -11.748883564062828f, A53 = 7.4955393428898365f, A54 = -0.09249506636175525f;
constexpr float A61 = 5.86145544294642f, A62 = -12.92096931784711f, A63 = 8.159367898576159f, A64 = -0.071584973281401f, A65 = -0.028269050394068383f;
constexpr float Bc1 = 0.09646076681806523f, Bc2 = 0.01f, Bc3 = 0.4798896504144996f;
constexpr float Bc4 = 1.379008574103742f, Bc5 = -3.290069515436081f, Bc6 = 2.324710524099774f;

__device__ inline float softplus_f(float x) {
  return fmaxf(x, 0.f) + log1pf(expf(-fabsf(x)));
}
__device__ inline float dot4(float4 w, float4 a) {
  return w.x * a.x + w.y * a.y + w.z * a.z + w.w * a.w;
}

} // namespace

// Persistent per-batch-tile NeuralCDE integrator, v3.
// 1024 threads (16 waves) per block, 4 batch rows, 256 blocks = 1/CU.
// Weight registers per thread: vw3 half-row (64) + vw2 eighth-row (16) +
// vw1 eighth-row (8) = 88 f32 -> fits the 128-VGPR budget the backend pins
// for 16-wave blocks (R1/R2 spilled at 176 weight regs: 39 GB scratch fetch).
__global__ __launch_bounds__(NT)
void ncde_kernel(const float* __restrict__ xs,
                 const float* __restrict__ iw1, const float* __restrict__ ib1,
                 const float* __restrict__ iw2, const float* __restrict__ ib2,
                 const float* __restrict__ iw3, const float* __restrict__ ib3,
                 const float* __restrict__ vw1, const float* __restrict__ vb1,
                 const float* __restrict__ vw2, const float* __restrict__ vb2,
                 const float* __restrict__ vw3, const float* __restrict__ vb3,
                 const float* __restrict__ lw,  const float* __restrict__ lb,
                 float* __restrict__ out)
{
  __shared__ float xs_l[BT][Tn * Dn];     // 8 KB control path
  __shared__ float y_l[BT][Hn];
  __shared__ float ys_l[BT][Hn];
  __shared__ float K_l[6][BT][Hn];
  __shared__ float h1_l[BT][Wn];
  __shared__ float h2_l[BT][Wn];
  __shared__ float part_l[8][BT][Wn];     // 16 KB k-split partials
  __shared__ float dxs_l[BT][Dn];
  __shared__ float lw_l[Hn];

  const int tid = threadIdx.x;
  const int oo  = tid & 127;              // output index for L1/L2
  const int g   = tid >> 7;               // k-split group 0..7
  const int b0  = blockIdx.x * BT;

  // ---- weights -> registers (88 f32/thread) ----
  float w3r[64];                          // vw3 row tid>>1, k-half tid&1
  {
    const float* p3 = vw3 + (tid >> 1) * Wn + (tid & 1) * 64;
    #pragma unroll
    for (int i = 0; i < 64; ++i) w3r[i] = p3[i];
  }
  float w2r[16];                          // vw2 row oo, k in [g*16, g*16+16)
  {
    const float* p2 = vw2 + oo * Wn + g * 16;
    #pragma unroll
    for (int i = 0; i < 16; ++i) w2r[i] = p2[i];
  }
  float w1r[8];                           // vw1 row oo, k in [g*8, g*8+8)
  {
    const float* p1 = vw1 + oo * Hn + g * 8;
    #pragma unroll
    for (int i = 0; i < 8; ++i) w1r[i] = p1[i];
  }
  const float b3r = vb3[tid >> 1];
  const float b2r = vb2[oo];
  const float b1r = vb1[oo];
  const float lb0 = lb[0];

  // ---- stage this block's xs rows ----
  if (tid < 512)
    ((float4*)&xs_l[0][0])[tid] = ((const float4*)(xs + b0 * Tn * Dn))[tid];
  if (tid < Hn) lw_l[tid] = lw[tid];
  __syncthreads();

  // ---- initial MLP (relu, relu, identity) ----
  if (tid < 512) {
    const int b = tid >> 7;
    float acc = ib1[oo];
    #pragma unroll
    for (int k = 0; k < Dn; ++k) acc += iw1[oo * Dn + k] * xs_l[b][k];
    h1_l[b][oo] = fmaxf(acc, 0.f);
  }
  __syncthreads();
  if (tid < 512) {
    const int b = tid >> 7;
    float acc = ib2[oo];
    const float4* wrow = (const float4*)(iw2 + oo * Wn);
    #pragma unroll
    for (int k4 = 0; k4 < Wn / 4; ++k4)
      acc += dot4(wrow[k4], *(const float4*)&h1_l[b][k4 * 4]);
    h2_l[b][oo] = fmaxf(acc, 0.f);
  }
  __syncthreads();
  if (tid < BT * Hn) {
    const int b = tid >> 6, h = tid & (Hn - 1);
    float acc = ib3[h];
    const float4* wrow = (const float4*)(iw3 + h * Wn);
    #pragma unroll
    for (int k4 = 0; k4 < Wn / 4; ++k4)
      acc += dot4(wrow[k4], *(const float4*)&h2_l[b][k4 * 4]);
    y_l[b][h] = acc;
  }
  __syncthreads();

  auto readout = [&](int t) {
    if (tid < BT * Hn) {
      const int wv = tid >> 6, h = tid & (Hn - 1);
      float p = lw_l[h] * y_l[wv][h];
      #pragma unroll
      for (int off = 32; off > 0; off >>= 1) p += __shfl_xor(p, off, 64);
      if (h == 0) out[(b0 + wv) * Tn + t] = 1.f / (1.f + expf(-(p + lb0)));
    }
  };
  readout(0);

  // ---- 63 Tsit5 steps ----
  for (int t = 0; t < Tn - 1; ++t) {
    if (tid < BT * Hn) {
      const int b = tid >> 6, h = tid & (Hn - 1);
      ys_l[b][h] = y_l[b][h];
    } else if (tid < BT * Hn + BT * Dn) {
      const int r = tid - BT * Hn;
      const int b = r >> 3, d = r & 7;
      dxs_l[b][d] = xs_l[b][(t + 1) * Dn + d] - xs_l[b][t * Dn + d];  // dt*dX/dt
    }
    __syncthreads();

    #pragma unroll
    for (int s = 0; s < 6; ++s) {
      // ---- vf L1: [4,64]->[4,128], k-split 8 ways (8 k-elems/thread) ----
      {
        float a[BT] = {0, 0, 0, 0};
        #pragma unroll
        for (int c = 0; c < 2; ++c) {
          #pragma unroll
          for (int b = 0; b < BT; ++b) {
            const float4 av = *(const float4*)&ys_l[b][g * 8 + c * 4];
            a[b] += w1r[c*4+0] * av.x + w1r[c*4+1] * av.y
                  + w1r[c*4+2] * av.z + w1r[c*4+3] * av.w;
          }
        }
        #pragma unroll
        for (int b = 0; b < BT; ++b) part_l[g][b][oo] = a[b];
      }
      __syncthreads();
      if (tid < 512) {
        const int b = tid >> 7;
        float acc = b1r;
        #pragma unroll
        for (int j = 0; j < 8; ++j) acc += part_l[j][b][oo];
        h1_l[b][oo] = softplus_f(acc);
      }
      __syncthreads();
      // ---- vf L2: [4,128]->[4,128], k-split 8 ways (16 k-elems/thread) ----
      {
        float a[BT] = {0, 0, 0, 0};
        #pragma unroll
        for (int c = 0; c < 4; ++c) {
          #pragma unroll
          for (int b = 0; b < BT; ++b) {
            const float4 av = *(const float4*)&h1_l[b][g * 16 + c * 4];
            a[b] += w2r[c*4+0] * av.x + w2r[c*4+1] * av.y
                  + w2r[c*4+2] * av.z + w2r[c*4+3] * av.w;
          }
        }
        #pragma unroll
        for (int b = 0; b < BT; ++b) part_l[g][b][oo] = a[b];
      }
      __syncthreads();
      if (tid < 512) {
        const int b = tid >> 7;
        float acc = b2r;
        #pragma unroll
        for (int j = 0; j < 8; ++j) acc += part_l[j][b][oo];
        h2_l[b][oo] = softplus_f(acc);
      }
      __syncthreads();
      // ---- vf L3: [4,128]->[4,512] (half-row/thread), tanh, einsum dx ----
      {
        float a[BT] = {0, 0, 0, 0};
        const int kh = (tid & 1) * 64;
        #pragma unroll
        for (int c = 0; c < 16; ++c) {
          #pragma unroll
          for (int b = 0; b < BT; ++b) {
            const float4 av = *(const float4*)&h2_l[b][kh + c * 4];
            a[b] += w3r[c*4+0] * av.x + w3r[c*4+1] * av.y
                  + w3r[c*4+2] * av.z + w3r[c*4+3] * av.w;
          }
        }
        const int d = (tid >> 1) & 7;     // row r3 = tid>>1 = h*8+d
        const int h = tid >> 4;
        #pragma unroll
        for (int b = 0; b < BT; ++b) {
          float p = a[b];
          p += __shfl_xor(p, 1, 64);                  // join k-halves
          p = tanhf(p + b3r) * dxs_l[b][d];
          p += __shfl_xor(p, 2, 64);                  // reduce over d (3 bits)
          p += __shfl_xor(p, 4, 64);
          p += __shfl_xor(p, 8, 64);
          if ((tid & 15) == 0) K_l[s][b][h] = p;
        }
      }
      __syncthreads();
      // ---- stage prep / final update ----
      if (tid < BT * Hn) {
        const int b = tid >> 6, h = tid & (Hn - 1);
        float v = y_l[b][h];
        if (s == 0)      v += A21 * K_l[0][b][h];
        else if (s == 1) v += A31 * K_l[0][b][h] + A32 * K_l[1][b][h];
        else if (s == 2) v += A41 * K_l[0][b][h] + A42 * K_l[1][b][h] + A43 * K_l[2][b][h];
        else if (s == 3) v += A51 * K_l[0][b][h] + A52 * K_l[1][b][h] + A53 * K_l[2][b][h] + A54 * K_l[3][b][h];
        else if (s == 4) v += A61 * K_l[0][b][h] + A62 * K_l[1][b][h] + A63 * K_l[2][b][h] + A64 * K_l[3][b][h] + A65 * K_l[4][b][h];
        else             v += Bc1 * K_l[0][b][h] + Bc2 * K_l[1][b][h] + Bc3 * K_l[2][b][h]
                            + Bc4 * K_l[3][b][h] + Bc5 * K_l[4][b][h] + Bc6 * K_l[5][b][h];
        if (s < 5) ys_l[b][h] = v; else y_l[b][h] = v;
      }
      __syncthreads();
    }
    readout(t + 1);
  }
}

extern "C" void kernel_launch(void* const* d_in, const int* in_sizes, int n_in,
                              void* d_out, int out_size, void* d_ws, size_t ws_size,
                              hipStream_t stream) {
  const float* xs  = (const float*)d_in[1];
  const float* iw1 = (const float*)d_in[2];
  const float* ib1 = (const float*)d_in[3];
  const float* iw2 = (const float*)d_in[4];
  const float* ib2 = (const float*)d_in[5];
  const float* iw3 = (const float*)d_in[6];
  const float* ib3 = (const float*)d_in[7];
  const float* vw1 = (const float*)d_in[8];
  const float* vb1 = (const float*)d_in[9];
  const float* vw2 = (const float*)d_in[10];
  const float* vb2 = (const float*)d_in[11];
  const float* vw3 = (const float*)d_in[12];
  const float* vb3 = (const float*)d_in[13];
  const float* lw  = (const float*)d_in[14];
  const float* lb  = (const float*)d_in[15];
  float* out = (float*)d_out;

  ncde_kernel<<<Bb / BT, NT, 0, stream>>>(xs, iw1, ib1, iw2, ib2, iw3, ib3,
                                          vw1, vb1, vw2, vb2, vw3, vb3, lw, lb, out);
}

// Round 4
// 22522.807 us; speedup vs baseline: 1.0105x; 1.0105x over previous
//
#include <hip/hip_runtime.h>
#include <math.h>

namespace {

constexpr int Bb = 1024;
constexpr int Tn = 64;
constexpr int Dn = 8;
constexpr int Hn = 64;
constexpr int Wn = 128;
constexpr int BT = 4;     // batch rows per block
constexpr int NT = 1024;  // threads per block (16 waves)

// Tsit5 tableau
constexpr float A21 = 0.161f;
constexpr float A31 = -0.008480655492356989f, A32 = 0.335480655492357f;
constexpr float A41 = 2.8971530571054935f, A42 = -6.359448489975075f, A43 = 4.3622954328695815f;
constexpr float A51 = 5.325864828439257f, A52 = -11.748883564062828f, A53 = 7.4955393428898365f, A54 = -0.09249506636175525f;
constexpr float A61 = 5.86145544294642f, A62 = -12.92096931784711f, A63 = 8.159367898576159f, A64 = -0.071584973281401f, A65 = -0.028269050394068383f;
constexpr float Bc1 = 0.09646076681806523f, Bc2 = 0.01f, Bc3 = 0.4798896504144996f;
constexpr float Bc4 = 1.379008574103742f, Bc5 = -3.290069515436081f, Bc6 = 2.324710524099774f;

__device__ inline float softplus_f(float x) {
  return fmaxf(x, 0.f) + log1pf(expf(-fabsf(x)));
}
__device__ inline float dot4(float4 w, float4 a) {
  return w.x * a.x + w.y * a.y + w.z * a.z + w.w * a.w;
}

} // namespace

// Persistent per-batch-tile NeuralCDE integrator, v4.
// 1024 threads (16 waves) per block, 4 batch rows, 256 blocks = 1/CU.
// Weight registers per thread: vw3 half-row (64) + vw2 eighth-row (16) +
// vw1 eighth-row (8) = 88 f32.
// amdgpu_num_vgpr(128): pin the RA budget. R1-R3 evidence: the backend's
// occupancy heuristic targets 2 WGs/CU (512thr->128, 1024thr->64 VGPRs)
// and demotes the weight arrays to scratch (40+ GB of scratch FETCH).
// 128 is the architectural max for a 16-wave WG (4 waves/SIMD x 128 = 512).
__attribute__((amdgpu_num_vgpr(128)))
__global__ __launch_bounds__(NT)
void ncde_kernel(const float* __restrict__ xs,
                 const float* __restrict__ iw1, const float* __restrict__ ib1,
                 const float* __restrict__ iw2, const float* __restrict__ ib2,
                 const float* __restrict__ iw3, const float* __restrict__ ib3,
                 const float* __restrict__ vw1, const float* __restrict__ vb1,
                 const float* __restrict__ vw2, const float* __restrict__ vb2,
                 const float* __restrict__ vw3, const float* __restrict__ vb3,
                 const float* __restrict__ lw,  const float* __restrict__ lb,
                 float* __restrict__ out)
{
  __shared__ float xs_l[BT][Tn * Dn];     // 8 KB control path
  __shared__ float y_l[BT][Hn];
  __shared__ float ys_l[BT][Hn];
  __shared__ float K_l[6][BT][Hn];
  __shared__ float h1_l[BT][Wn];
  __shared__ float h2_l[BT][Wn];
  __shared__ float part_l[8][BT][Wn];     // 16 KB k-split partials
  __shared__ float dxs_l[BT][Dn];
  __shared__ float lw_l[Hn];

  const int tid = threadIdx.x;
  const int oo  = tid & 127;              // output index for L1/L2
  const int g   = tid >> 7;               // k-split group 0..7
  const int b0  = blockIdx.x * BT;

  // ---- weights -> registers (88 f32/thread) ----
  float w3r[64];                          // vw3 row tid>>1, k-half tid&1
  {
    const float* p3 = vw3 + (tid >> 1) * Wn + (tid & 1) * 64;
    #pragma unroll
    for (int i = 0; i < 64; ++i) w3r[i] = p3[i];
  }
  float w2r[16];                          // vw2 row oo, k in [g*16, g*16+16)
  {
    const float* p2 = vw2 + oo * Wn + g * 16;
    #pragma unroll
    for (int i = 0; i < 16; ++i) w2r[i] = p2[i];
  }
  float w1r[8];                           // vw1 row oo, k in [g*8, g*8+8)
  {
    const float* p1 = vw1 + oo * Hn + g * 8;
    #pragma unroll
    for (int i = 0; i < 8; ++i) w1r[i] = p1[i];
  }
  const float b3r = vb3[tid >> 1];
  const float b2r = vb2[oo];
  const float b1r = vb1[oo];
  const float lb0 = lb[0];

  // ---- stage this block's xs rows ----
  if (tid < 512)
    ((float4*)&xs_l[0][0])[tid] = ((const float4*)(xs + b0 * Tn * Dn))[tid];
  if (tid < Hn) lw_l[tid] = lw[tid];
  __syncthreads();

  // ---- initial MLP (relu, relu, identity) ----
  if (tid < 512) {
    const int b = tid >> 7;
    float acc = ib1[oo];
    #pragma unroll
    for (int k = 0; k < Dn; ++k) acc += iw1[oo * Dn + k] * xs_l[b][k];
    h1_l[b][oo] = fmaxf(acc, 0.f);
  }
  __syncthreads();
  if (tid < 512) {
    const int b = tid >> 7;
    float acc = ib2[oo];
    const float4* wrow = (const float4*)(iw2 + oo * Wn);
    #pragma unroll
    for (int k4 = 0; k4 < Wn / 4; ++k4)
      acc += dot4(wrow[k4], *(const float4*)&h1_l[b][k4 * 4]);
    h2_l[b][oo] = fmaxf(acc, 0.f);
  }
  __syncthreads();
  if (tid < BT * Hn) {
    const int b = tid >> 6, h = tid & (Hn - 1);
    float acc = ib3[h];
    const float4* wrow = (const float4*)(iw3 + h * Wn);
    #pragma unroll
    for (int k4 = 0; k4 < Wn / 4; ++k4)
      acc += dot4(wrow[k4], *(const float4*)&h2_l[b][k4 * 4]);
    y_l[b][h] = acc;
  }
  __syncthreads();

  auto readout = [&](int t) {
    if (tid < BT * Hn) {
      const int wv = tid >> 6, h = tid & (Hn - 1);
      float p = lw_l[h] * y_l[wv][h];
      #pragma unroll
      for (int off = 32; off > 0; off >>= 1) p += __shfl_xor(p, off, 64);
      if (h == 0) out[(b0 + wv) * Tn + t] = 1.f / (1.f + expf(-(p + lb0)));
    }
  };
  readout(0);

  // ---- 63 Tsit5 steps ----
  for (int t = 0; t < Tn - 1; ++t) {
    if (tid < BT * Hn) {
      const int b = tid >> 6, h = tid & (Hn - 1);
      ys_l[b][h] = y_l[b][h];
    } else if (tid < BT * Hn + BT * Dn) {
      const int r = tid - BT * Hn;
      const int b = r >> 3, d = r & 7;
      dxs_l[b][d] = xs_l[b][(t + 1) * Dn + d] - xs_l[b][t * Dn + d];  // dt*dX/dt
    }
    __syncthreads();

    #pragma unroll
    for (int s = 0; s < 6; ++s) {
      // ---- vf L1: [4,64]->[4,128], k-split 8 ways (8 k-elems/thread) ----
      {
        float a[BT] = {0, 0, 0, 0};
        #pragma unroll
        for (int c = 0; c < 2; ++c) {
          #pragma unroll
          for (int b = 0; b < BT; ++b) {
            const float4 av = *(const float4*)&ys_l[b][g * 8 + c * 4];
            a[b] += w1r[c*4+0] * av.x + w1r[c*4+1] * av.y
                  + w1r[c*4+2] * av.z + w1r[c*4+3] * av.w;
          }
        }
        #pragma unroll
        for (int b = 0; b < BT; ++b) part_l[g][b][oo] = a[b];
      }
      __syncthreads();
      if (tid < 512) {
        const int b = tid >> 7;
        float acc = b1r;
        #pragma unroll
        for (int j = 0; j < 8; ++j) acc += part_l[j][b][oo];
        h1_l[b][oo] = softplus_f(acc);
      }
      __syncthreads();
      // ---- vf L2: [4,128]->[4,128], k-split 8 ways (16 k-elems/thread) ----
      {
        float a[BT] = {0, 0, 0, 0};
        #pragma unroll
        for (int c = 0; c < 4; ++c) {
          #pragma unroll
          for (int b = 0; b < BT; ++b) {
            const float4 av = *(const float4*)&h1_l[b][g * 16 + c * 4];
            a[b] += w2r[c*4+0] * av.x + w2r[c*4+1] * av.y
                  + w2r[c*4+2] * av.z + w2r[c*4+3] * av.w;
          }
        }
        #pragma unroll
        for (int b = 0; b < BT; ++b) part_l[g][b][oo] = a[b];
      }
      __syncthreads();
      if (tid < 512) {
        const int b = tid >> 7;
        float acc = b2r;
        #pragma unroll
        for (int j = 0; j < 8; ++j) acc += part_l[j][b][oo];
        h2_l[b][oo] = softplus_f(acc);
      }
      __syncthreads();
      // ---- vf L3: [4,128]->[4,512] (half-row/thread), tanh, einsum dx ----
      {
        float a[BT] = {0, 0, 0, 0};
        const int kh = (tid & 1) * 64;
        #pragma unroll
        for (int c = 0; c < 16; ++c) {
          #pragma unroll
          for (int b = 0; b < BT; ++b) {
            const float4 av = *(const float4*)&h2_l[b][kh + c * 4];
            a[b] += w3r[c*4+0] * av.x + w3r[c*4+1] * av.y
                  + w3r[c*4+2] * av.z + w3r[c*4+3] * av.w;
          }
        }
        const int d = (tid >> 1) & 7;     // row r3 = tid>>1 = h*8+d
        const int h = tid >> 4;
        #pragma unroll
        for (int b = 0; b < BT; ++b) {
          float p = a[b];
          p += __shfl_xor(p, 1, 64);                  // join k-halves
          p = tanhf(p + b3r) * dxs_l[b][d];
          p += __shfl_xor(p, 2, 64);                  // reduce over d (3 bits)
          p += __shfl_xor(p, 4, 64);
          p += __shfl_xor(p, 8, 64);
          if ((tid & 15) == 0) K_l[s][b][h] = p;
        }
      }
      __syncthreads();
      // ---- stage prep / final update ----
      if (tid < BT * Hn) {
        const int b = tid >> 6, h = tid & (Hn - 1);
        float v = y_l[b][h];
        if (s == 0)      v += A21 * K_l[0][b][h];
        else if (s == 1) v += A31 * K_l[0][b][h] + A32 * K_l[1][b][h];
        else if (s == 2) v += A41 * K_l[0][b][h] + A42 * K_l[1][b][h] + A43 * K_l[2][b][h];
        else if (s == 3) v += A51 * K_l[0][b][h] + A52 * K_l[1][b][h] + A53 * K_l[2][b][h] + A54 * K_l[3][b][h];
        else if (s == 4) v += A61 * K_l[0][b][h] + A62 * K_l[1][b][h] + A63 * K_l[2][b][h] + A64 * K_l[3][b][h] + A65 * K_l[4][b][h];
        else             v += Bc1 * K_l[0][b][h] + Bc2 * K_l[1][b][h] + Bc3 * K_l[2][b][h]
                            + Bc4 * K_l[3][b][h] + Bc5 * K_l[4][b][h] + Bc6 * K_l[5][b][h];
        if (s < 5) ys_l[b][h] = v; else y_l[b][h] = v;
      }
      __syncthreads();
    }
    readout(t + 1);
  }
}

extern "C" void kernel_launch(void* const* d_in, const int* in_sizes, int n_in,
                              void* d_out, int out_size, void* d_ws, size_t ws_size,
                              hipStream_t stream) {
  const float* xs  = (const float*)d_in[1];
  const float* iw1 = (const float*)d_in[2];
  const float* ib1 = (const float*)d_in[3];
  const float* iw2 = (const float*)d_in[4];
  const float* ib2 = (const float*)d_in[5];
  const float* iw3 = (const float*)d_in[6];
  const float* ib3 = (const float*)d_in[7];
  const float* vw1 = (const float*)d_in[8];
  const float* vb1 = (const float*)d_in[9];
  const float* vw2 = (const float*)d_in[10];
  const float* vb2 = (const float*)d_in[11];
  const float* vw3 = (const float*)d_in[12];
  const float* vb3 = (const float*)d_in[13];
  const float* lw  = (const float*)d_in[14];
  const float* lb  = (const float*)d_in[15];
  float* out = (float*)d_out;

  ncde_kernel<<<Bb / BT, NT, 0, stream>>>(xs, iw1, ib1, iw2, ib2, iw3, ib3,
                                          vw1, vb1, vw2, vb2, vw3, vb3, lw, lb, out);
}